// Round 11
// baseline (80.908 us; speedup 1.0000x reference)
//
#include <hip/hip_runtime.h>

typedef __bf16 bf16x8 __attribute__((ext_vector_type(8)));
typedef float  f32x4  __attribute__((ext_vector_type(4)));

__device__ __forceinline__ unsigned short f2bf(float f) {
  unsigned u = __float_as_uint(f);
  u = u + 0x7fffu + ((u >> 16) & 1u);   // RNE
  return (unsigned short)(u >> 16);
}

// K0: convert x (f32) -> xb (bf16), 8 elems/thread
__global__ __launch_bounds__(256) void cvt_bf16(
    const float* __restrict__ x, unsigned short* __restrict__ xb, int total8) {
  int i = blockIdx.x * 256 + threadIdx.x;
  if (i >= total8) return;
  const float4* p = (const float4*)(x + (size_t)i * 8);
  float4 a = p[0], b = p[1];
  union { unsigned short u[8]; uint4 v; } r;
  r.u[0] = f2bf(a.x); r.u[1] = f2bf(a.y); r.u[2] = f2bf(a.z); r.u[3] = f2bf(a.w);
  r.u[4] = f2bf(b.x); r.u[5] = f2bf(b.y); r.u[6] = f2bf(b.z); r.u[7] = f2bf(b.w);
  ((uint4*)xb)[i] = r.v;
}

// K1: mean aggregation. PERSISTENT waves: each wave grid-strides over nodes
// (~12 nodes/wave) so degree variance averages out and blocks retire
// together -> higher time-averaged occupancy. Inner loop = round-10
// paired-row dword gathers (2 edges / 1 vmem instr, SGPR bases, minimal VALU).
template <bool AGGBF>
__global__ __launch_bounds__(256) void agg_pair(
    const unsigned short* __restrict__ xb, const int* __restrict__ row,
    const int* __restrict__ colptr, float* __restrict__ aggf,
    unsigned short* __restrict__ aggb, int N) {
  int lane = threadIdx.x & 63;
  int wstride = gridDim.x * 4;
  bool hi = lane >= 32;
  int  fp4 = (lane & 31) * 4;     // byte offset: features 2fp, 2fp+1
  int  li  = lane & 15;

  for (int wid = blockIdx.x * 4 + (threadIdx.x >> 6); wid < N; wid += wstride) {
    int s = __builtin_amdgcn_readfirstlane(colptr[wid]);
    int e = __builtin_amdgcn_readfirstlane(colptr[wid + 1]);
    float acc0 = 0.f, acc1 = 0.f;
    int deg   = e - s;
    int nfull = deg & ~15;

    // ---- main: full batches of 16 edges (8 pair-gathers), no predication ----
    if (nfull) {
      int t = s;
      int idxv = row[t + li];                  // 16 indices, one trip
      for (;;) {
        int nt = t + 16;
        bool more = nt < s + nfull;
        int id[16];
        #pragma unroll
        for (int j = 0; j < 16; ++j) id[j] = __builtin_amdgcn_readlane(idxv, j);
        if (more) idxv = row[nt + li];         // prefetch under gathers
        unsigned g[8];
        #pragma unroll
        for (int q = 0; q < 8; ++q) {
          int a = id[2 * q], b = id[2 * q + 1];
          int mn = min(a, b);
          int df = (max(a, b) - mn) * 128;     // SALU
          const char* base = (const char*)xb + (size_t)mn * 128;
          int voff = (hi ? df : 0) + fp4;      // cndmask + add
          g[q] = *(const unsigned*)(base + voff);
        }
        #pragma unroll
        for (int q = 0; q < 8; ++q) {
          acc0 += __uint_as_float(g[q] << 16);
          acc1 += __uint_as_float(g[q] & 0xffff0000u);
        }
        if (!more) break;
        t = nt;
      }
    }

    // ---- tail: rem in 1..15 edges, uniform pair count ----
    int t = s + nfull;
    int rem = e - t;
    if (rem > 0) {
      int idxv = row[min(t + li, e - 1)];
      int id[16];
      #pragma unroll
      for (int j = 0; j < 16; ++j) id[j] = __builtin_amdgcn_readlane(idxv, j);
      int npairs = (rem + 1) >> 1;
      bool odd = (rem & 1) != 0;
      unsigned g[8];
      #pragma unroll
      for (int q = 0; q < 8; ++q) {
        if (q < npairs) {                      // uniform branch
          int a = id[2 * q], b = id[2 * q + 1];
          int mn = min(a, b);
          int df = (max(a, b) - mn) * 128;
          const char* base = (const char*)xb + (size_t)mn * 128;
          int voff = (hi ? df : 0) + fp4;
          g[q] = *(const unsigned*)(base + voff);
        }
      }
      #pragma unroll
      for (int q = 0; q < 8; ++q) {
        if (q < npairs) {
          unsigned v = g[q];
          if (odd && q == npairs - 1)          // lone edge: count once
            v = hi ? 0u : v;
          acc0 += __uint_as_float(v << 16);
          acc1 += __uint_as_float(v & 0xffff0000u);
        }
      }
    }

    // fold the two edge-halves (lane j <-> j+32)
    acc0 += __shfl_xor(acc0, 32);
    acc1 += __shfl_xor(acc1, 32);

    float sc = (deg > 0) ? (1.0f / (float)deg) : 0.0f;
    if (lane < 32) {                           // 32 lanes x 4B = 128B row
      if (AGGBF) {
        unsigned p = (unsigned)f2bf(acc0 * sc) | ((unsigned)f2bf(acc1 * sc) << 16);
        *(unsigned*)(aggb + (size_t)wid * 64 + (lane & 31) * 2) = p;
      } else {
        float2 p; p.x = acc0 * sc; p.y = acc1 * sc;
        *(float2*)(aggf + (size_t)wid * 64 + (lane & 31) * 2) = p;
      }
    }
  }
}

// K1 fallback (no-ws): f32 gathers, persistent-wave variant.
__global__ __launch_bounds__(256) void agg_f32(
    const float* __restrict__ x, const int* __restrict__ row,
    const int* __restrict__ colptr, float* __restrict__ aggf, int N) {
  int lane = threadIdx.x & 63;
  int wstride = gridDim.x * 4;
  for (int wid = blockIdx.x * 4 + (threadIdx.x >> 6); wid < N; wid += wstride) {
    int s = __builtin_amdgcn_readfirstlane(colptr[wid]);
    int e = __builtin_amdgcn_readfirstlane(colptr[wid + 1]);
    float acc = 0.0f;
    int t = s;
    if (t < e) {
      int li = lane & 15;
      int myidx = row[min(t + li, e - 1)];
      for (;;) {
        int lim  = e - t;
        int nt   = t + 16;
        bool more = nt < e;
        int idx[16];
        #pragma unroll
        for (int j = 0; j < 16; ++j) idx[j] = __builtin_amdgcn_readlane(myidx, j);
        if (more) myidx = row[min(nt + li, e - 1)];
        float g[16];
        #pragma unroll
        for (int j = 0; j < 16; ++j) g[j] = x[(size_t)idx[j] * 64 + lane];
        if (lim < 16) {
          #pragma unroll
          for (int j = 0; j < 16; ++j) if (j >= lim) g[j] = 0.0f;
        }
        acc += (((g[0] + g[1]) + (g[2] + g[3])) + ((g[4] + g[5]) + (g[6] + g[7])))
             + (((g[8] + g[9]) + (g[10] + g[11])) + ((g[12] + g[13]) + (g[14] + g[15])));
        if (!more) break;
        t = nt;
      }
    }
    int deg = e - s;
    aggf[(size_t)wid * 64 + lane] = (deg > 0) ? (acc / (float)deg) : 0.0f;
  }
}

// K2: out[n] = b + [agg|x] @ W^T via bf16 MFMA 16x16x32.
template <bool BF, bool AGGBF>
__global__ __launch_bounds__(256) void sage_mm(
    const float* __restrict__ x, const unsigned short* __restrict__ xb,
    const unsigned short* __restrict__ aggb,
    const float* __restrict__ W, const float* __restrict__ b,
    float* __restrict__ out, int N) {
  __shared__ unsigned short ft[128][136];
  int tid = threadIdx.x;
  int l = tid & 63, w = tid >> 6;
  int colr = l & 15, kg = l >> 4;
  int n0 = blockIdx.x * 128;
  int rows = N - n0; if (rows > 128) rows = 128;

  bf16x8 bfrag[4][4];
  float bias[4];
  #pragma unroll
  for (int c = 0; c < 4; ++c) {
    bias[c] = b[c * 16 + colr];
    #pragma unroll
    for (int kq = 0; kq < 4; ++kq) {
      const float* wp = W + (size_t)(c * 16 + colr) * 128 + kq * 32 + kg * 8;
      float4 wa = *(const float4*)wp;
      float4 wb = *(const float4*)(wp + 4);
      union { unsigned short u[8]; bf16x8 v; } r;
      r.u[0] = f2bf(wa.x); r.u[1] = f2bf(wa.y); r.u[2] = f2bf(wa.z); r.u[3] = f2bf(wa.w);
      r.u[4] = f2bf(wb.x); r.u[5] = f2bf(wb.y); r.u[6] = f2bf(wb.z); r.u[7] = f2bf(wb.w);
      bfrag[c][kq] = r.v;
    }
  }

  const float* aggsrcf = out + (size_t)n0 * 64;
  #pragma unroll
  for (int it = 0; it < 4; ++it) {
    int flat = it * 2048 + tid * 8;
    int n = flat >> 6, k = flat & 63;
    { // agg half -> ft[n][0..63]
      uint4 v = make_uint4(0, 0, 0, 0);
      if (n < rows) {
        if (AGGBF) {
          v = *(const uint4*)(aggb + ((size_t)(n0 + n) * 64 + k));
        } else {
          const float4* p = (const float4*)(aggsrcf + (size_t)n * 64 + k);
          float4 a = p[0], bb = p[1];
          union { unsigned short u[8]; uint4 vv; } r;
          r.u[0] = f2bf(a.x);  r.u[1] = f2bf(a.y);  r.u[2] = f2bf(a.z);  r.u[3] = f2bf(a.w);
          r.u[4] = f2bf(bb.x); r.u[5] = f2bf(bb.y); r.u[6] = f2bf(bb.z); r.u[7] = f2bf(bb.w);
          v = r.vv;
        }
      }
      *(uint4*)&ft[n][k] = v;
    }
    { // x half -> ft[n][64..127]
      uint4 v = make_uint4(0, 0, 0, 0);
      if (n < rows) {
        if (BF) {
          v = *(const uint4*)(xb + ((size_t)(n0 + n) * 64 + k));
        } else {
          const float4* p = (const float4*)(x + (size_t)(n0 + n) * 64 + k);
          float4 a = p[0], bb = p[1];
          union { unsigned short u[8]; uint4 vv; } r;
          r.u[0] = f2bf(a.x);  r.u[1] = f2bf(a.y);  r.u[2] = f2bf(a.z);  r.u[3] = f2bf(a.w);
          r.u[4] = f2bf(bb.x); r.u[5] = f2bf(bb.y); r.u[6] = f2bf(bb.z); r.u[7] = f2bf(bb.w);
          v = r.vv;
        }
      }
      *(uint4*)&ft[n][64 + k] = v;
    }
  }
  __syncthreads();

  f32x4 acc[2][4];
  #pragma unroll
  for (int c = 0; c < 4; ++c) {
    acc[0][c] = (f32x4){bias[c], bias[c], bias[c], bias[c]};
    acc[1][c] = acc[0][c];
  }

  #pragma unroll
  for (int kq = 0; kq < 4; ++kq) {
    bf16x8 a0 = *(const bf16x8*)&ft[w * 32 + colr][kq * 32 + kg * 8];
    bf16x8 a1 = *(const bf16x8*)&ft[w * 32 + 16 + colr][kq * 32 + kg * 8];
    #pragma unroll
    for (int c = 0; c < 4; ++c) {
      acc[0][c] = __builtin_amdgcn_mfma_f32_16x16x32_bf16(a0, bfrag[c][kq], acc[0][c], 0, 0, 0);
      acc[1][c] = __builtin_amdgcn_mfma_f32_16x16x32_bf16(a1, bfrag[c][kq], acc[1][c], 0, 0, 0);
    }
  }

  #pragma unroll
  for (int m = 0; m < 2; ++m) {
    int nodeb = n0 + w * 32 + m * 16 + kg * 4;
    #pragma unroll
    for (int c = 0; c < 4; ++c) {
      #pragma unroll
      for (int r = 0; r < 4; ++r) {
        int node = nodeb + r;
        if (node < N) out[(size_t)node * 64 + c * 16 + colr] = acc[m][c][r];
      }
    }
  }
}

extern "C" void kernel_launch(void* const* d_in, const int* in_sizes, int n_in,
                              void* d_out, int out_size, void* d_ws, size_t ws_size,
                              hipStream_t stream) {
  const float* x      = (const float*)d_in[0];
  const int*   row    = (const int*)d_in[1];
  const int*   colptr = (const int*)d_in[2];
  const float* W      = (const float*)d_in[3];
  const float* b      = (const float*)d_in[4];
  float* out = (float*)d_out;

  int N = in_sizes[0] / 64;
  size_t nb_bf = (size_t)N * 64 * 2;   // bf16 x copy
  unsigned short* xb = (unsigned short*)d_ws;
  unsigned short* xa = (unsigned short*)((char*)d_ws + nb_bf);  // bf16 agg

  int total8 = N * 8;
  int nbc = (total8 + 255) / 256;
  int nba = 2048;                      // persistent: 8192 waves, ~12 nodes each
  if (nba > (N + 3) / 4) nba = (N + 3) / 4;
  int nbm = (N + 127) / 128;

  if (ws_size >= 2 * nb_bf) {
    cvt_bf16<<<nbc, 256, 0, stream>>>(x, xb, total8);
    agg_pair<true><<<nba, 256, 0, stream>>>(xb, row, colptr, out, xa, N);
    sage_mm<true, true><<<nbm, 256, 0, stream>>>(x, xb, xa, W, b, out, N);
  } else if (ws_size >= nb_bf) {
    cvt_bf16<<<nbc, 256, 0, stream>>>(x, xb, total8);
    agg_pair<false><<<nba, 256, 0, stream>>>(xb, row, colptr, out, xa, N);
    sage_mm<true, false><<<nbm, 256, 0, stream>>>(x, xb, xa, W, b, out, N);
  } else {
    agg_f32<<<nba, 256, 0, stream>>>(x, row, colptr, out, N);
    sage_mm<false, false><<<nbm, 256, 0, stream>>>(x, xb, xa, W, b, out, N);
  }
}

// Round 12
// 77.612 us; speedup vs baseline: 1.0425x; 1.0425x over previous
//
#include <hip/hip_runtime.h>

typedef __bf16 bf16x8 __attribute__((ext_vector_type(8)));
typedef float  f32x4  __attribute__((ext_vector_type(4)));

__device__ __forceinline__ unsigned short f2bf(float f) {
  unsigned u = __float_as_uint(f);
  u = u + 0x7fffu + ((u >> 16) & 1u);   // RNE
  return (unsigned short)(u >> 16);
}

// K0: convert x (f32) -> xb (bf16), 8 elems/thread
__global__ __launch_bounds__(256) void cvt_bf16(
    const float* __restrict__ x, unsigned short* __restrict__ xb, int total8) {
  int i = blockIdx.x * 256 + threadIdx.x;
  if (i >= total8) return;
  const float4* p = (const float4*)(x + (size_t)i * 8);
  float4 a = p[0], b = p[1];
  union { unsigned short u[8]; uint4 v; } r;
  r.u[0] = f2bf(a.x); r.u[1] = f2bf(a.y); r.u[2] = f2bf(a.z); r.u[3] = f2bf(a.w);
  r.u[4] = f2bf(b.x); r.u[5] = f2bf(b.y); r.u[6] = f2bf(b.z); r.u[7] = f2bf(b.w);
  ((uint4*)xb)[i] = r.v;
}

// K1: mean aggregation, 1 node/wave, paired-row dword gathers with minimal
// VALU. Pair of edges (A,B): SALU computes base=min(A,B)*128 and df=|A-B|*128;
// lanes 0-31 read base+fp4, lanes 32-63 read base+df+fp4 (one cndmask + add).
// A sum is order-independent, so which half gets which edge doesn't matter.
// Full batches (16 edges) carry zero predication; tail uses uniform branches.
// NOTE (roofline): agg is bound by 1.6M random 128B line fetches at the
// per-CU outstanding-miss cap (~34 lines @ ~600cyc) -> ~46us floor; verified
// invariant across 4 structural variants (r6/r9/r10/r11).
template <bool AGGBF>
__global__ __launch_bounds__(256) void agg_pair(
    const unsigned short* __restrict__ xb, const int* __restrict__ row,
    const int* __restrict__ colptr, float* __restrict__ aggf,
    unsigned short* __restrict__ aggb, int N) {
  int wid  = blockIdx.x * 4 + (threadIdx.x >> 6);
  int lane = threadIdx.x & 63;
  if (wid >= N) return;
  int s = __builtin_amdgcn_readfirstlane(colptr[wid]);
  int e = __builtin_amdgcn_readfirstlane(colptr[wid + 1]);
  bool hi = lane >= 32;
  int  fp4 = (lane & 31) * 4;     // byte offset: features 2fp, 2fp+1
  int  li  = lane & 15;
  float acc0 = 0.f, acc1 = 0.f;

  int deg   = e - s;
  int nfull = deg & ~15;

  // ---- main: full batches of 16 edges (8 pair-gathers), no predication ----
  if (nfull) {
    int t = s;
    int idxv = row[t + li];                  // 16 indices, one trip
    for (;;) {
      int nt = t + 16;
      bool more = nt < s + nfull;
      int id[16];
      #pragma unroll
      for (int j = 0; j < 16; ++j) id[j] = __builtin_amdgcn_readlane(idxv, j);
      if (more) idxv = row[nt + li];         // prefetch under gathers
      unsigned g[8];
      #pragma unroll
      for (int q = 0; q < 8; ++q) {
        int a = id[2 * q], b = id[2 * q + 1];
        int mn = min(a, b);
        int df = (max(a, b) - mn) * 128;     // SALU
        const char* base = (const char*)xb + (size_t)mn * 128;
        int voff = (hi ? df : 0) + fp4;      // cndmask + add
        g[q] = *(const unsigned*)(base + voff);
      }
      #pragma unroll
      for (int q = 0; q < 8; ++q) {
        acc0 += __uint_as_float(g[q] << 16);
        acc1 += __uint_as_float(g[q] & 0xffff0000u);
      }
      if (!more) break;
      t = nt;
    }
  }

  // ---- tail: rem in 1..15 edges, uniform pair count ----
  int t = s + nfull;
  int rem = e - t;
  if (rem > 0) {
    int idxv = row[min(t + li, e - 1)];
    int id[16];
    #pragma unroll
    for (int j = 0; j < 16; ++j) id[j] = __builtin_amdgcn_readlane(idxv, j);
    int npairs = (rem + 1) >> 1;
    bool odd = (rem & 1) != 0;
    unsigned g[8];
    #pragma unroll
    for (int q = 0; q < 8; ++q) {
      if (q < npairs) {                      // uniform branch
        int a = id[2 * q], b = id[2 * q + 1];
        int mn = min(a, b);
        int df = (max(a, b) - mn) * 128;
        const char* base = (const char*)xb + (size_t)mn * 128;
        int voff = (hi ? df : 0) + fp4;
        g[q] = *(const unsigned*)(base + voff);
      }
    }
    #pragma unroll
    for (int q = 0; q < 8; ++q) {
      if (q < npairs) {
        unsigned v = g[q];
        if (odd && q == npairs - 1)          // lone edge: count once
          v = hi ? 0u : v;
        acc0 += __uint_as_float(v << 16);
        acc1 += __uint_as_float(v & 0xffff0000u);
      }
    }
  }

  // fold the two edge-halves (lane j <-> j+32)
  acc0 += __shfl_xor(acc0, 32);
  acc1 += __shfl_xor(acc1, 32);

  float sc = (deg > 0) ? (1.0f / (float)deg) : 0.0f;
  if (lane < 32) {                           // 32 lanes x 4B = 128B row
    if (AGGBF) {
      unsigned p = (unsigned)f2bf(acc0 * sc) | ((unsigned)f2bf(acc1 * sc) << 16);
      *(unsigned*)(aggb + (size_t)wid * 64 + (lane & 31) * 2) = p;
    } else {
      float2 p; p.x = acc0 * sc; p.y = acc1 * sc;
      *(float2*)(aggf + (size_t)wid * 64 + (lane & 31) * 2) = p;
    }
  }
}

// K1 fallback (no-ws): f32 gathers.
__global__ __launch_bounds__(256) void agg_f32(
    const float* __restrict__ x, const int* __restrict__ row,
    const int* __restrict__ colptr, float* __restrict__ aggf, int N) {
  int wid  = blockIdx.x * 4 + (threadIdx.x >> 6);
  int lane = threadIdx.x & 63;
  if (wid >= N) return;
  int s = __builtin_amdgcn_readfirstlane(colptr[wid]);
  int e = __builtin_amdgcn_readfirstlane(colptr[wid + 1]);
  float acc = 0.0f;
  int t = s;
  if (t < e) {
    int li = lane & 15;
    int myidx = row[min(t + li, e - 1)];
    for (;;) {
      int lim  = e - t;
      int nt   = t + 16;
      bool more = nt < e;
      int idx[16];
      #pragma unroll
      for (int j = 0; j < 16; ++j) idx[j] = __builtin_amdgcn_readlane(myidx, j);
      if (more) myidx = row[min(nt + li, e - 1)];
      float g[16];
      #pragma unroll
      for (int j = 0; j < 16; ++j) g[j] = x[(size_t)idx[j] * 64 + lane];
      if (lim < 16) {
        #pragma unroll
        for (int j = 0; j < 16; ++j) if (j >= lim) g[j] = 0.0f;
      }
      acc += (((g[0] + g[1]) + (g[2] + g[3])) + ((g[4] + g[5]) + (g[6] + g[7])))
           + (((g[8] + g[9]) + (g[10] + g[11])) + ((g[12] + g[13]) + (g[14] + g[15])));
      if (!more) break;
      t = nt;
    }
  }
  int deg = e - s;
  aggf[(size_t)wid * 64 + lane] = (deg > 0) ? (acc / (float)deg) : 0.0f;
}

// K2: out[n] = b + [agg|x] @ W^T via bf16 MFMA 16x16x32.
template <bool BF, bool AGGBF>
__global__ __launch_bounds__(256) void sage_mm(
    const float* __restrict__ x, const unsigned short* __restrict__ xb,
    const unsigned short* __restrict__ aggb,
    const float* __restrict__ W, const float* __restrict__ b,
    float* __restrict__ out, int N) {
  __shared__ unsigned short ft[128][136];
  int tid = threadIdx.x;
  int l = tid & 63, w = tid >> 6;
  int colr = l & 15, kg = l >> 4;
  int n0 = blockIdx.x * 128;
  int rows = N - n0; if (rows > 128) rows = 128;

  bf16x8 bfrag[4][4];
  float bias[4];
  #pragma unroll
  for (int c = 0; c < 4; ++c) {
    bias[c] = b[c * 16 + colr];
    #pragma unroll
    for (int kq = 0; kq < 4; ++kq) {
      const float* wp = W + (size_t)(c * 16 + colr) * 128 + kq * 32 + kg * 8;
      float4 wa = *(const float4*)wp;
      float4 wb = *(const float4*)(wp + 4);
      union { unsigned short u[8]; bf16x8 v; } r;
      r.u[0] = f2bf(wa.x); r.u[1] = f2bf(wa.y); r.u[2] = f2bf(wa.z); r.u[3] = f2bf(wa.w);
      r.u[4] = f2bf(wb.x); r.u[5] = f2bf(wb.y); r.u[6] = f2bf(wb.z); r.u[7] = f2bf(wb.w);
      bfrag[c][kq] = r.v;
    }
  }

  const float* aggsrcf = out + (size_t)n0 * 64;
  #pragma unroll
  for (int it = 0; it < 4; ++it) {
    int flat = it * 2048 + tid * 8;
    int n = flat >> 6, k = flat & 63;
    { // agg half -> ft[n][0..63]
      uint4 v = make_uint4(0, 0, 0, 0);
      if (n < rows) {
        if (AGGBF) {
          v = *(const uint4*)(aggb + ((size_t)(n0 + n) * 64 + k));
        } else {
          const float4* p = (const float4*)(aggsrcf + (size_t)n * 64 + k);
          float4 a = p[0], bb = p[1];
          union { unsigned short u[8]; uint4 vv; } r;
          r.u[0] = f2bf(a.x);  r.u[1] = f2bf(a.y);  r.u[2] = f2bf(a.z);  r.u[3] = f2bf(a.w);
          r.u[4] = f2bf(bb.x); r.u[5] = f2bf(bb.y); r.u[6] = f2bf(bb.z); r.u[7] = f2bf(bb.w);
          v = r.vv;
        }
      }
      *(uint4*)&ft[n][k] = v;
    }
    { // x half -> ft[n][64..127]
      uint4 v = make_uint4(0, 0, 0, 0);
      if (n < rows) {
        if (BF) {
          v = *(const uint4*)(xb + ((size_t)(n0 + n) * 64 + k));
        } else {
          const float4* p = (const float4*)(x + (size_t)(n0 + n) * 64 + k);
          float4 a = p[0], bb = p[1];
          union { unsigned short u[8]; uint4 vv; } r;
          r.u[0] = f2bf(a.x);  r.u[1] = f2bf(a.y);  r.u[2] = f2bf(a.z);  r.u[3] = f2bf(a.w);
          r.u[4] = f2bf(bb.x); r.u[5] = f2bf(bb.y); r.u[6] = f2bf(bb.z); r.u[7] = f2bf(bb.w);
          v = r.vv;
        }
      }
      *(uint4*)&ft[n][64 + k] = v;
    }
  }
  __syncthreads();

  f32x4 acc[2][4];
  #pragma unroll
  for (int c = 0; c < 4; ++c) {
    acc[0][c] = (f32x4){bias[c], bias[c], bias[c], bias[c]};
    acc[1][c] = acc[0][c];
  }

  #pragma unroll
  for (int kq = 0; kq < 4; ++kq) {
    bf16x8 a0 = *(const bf16x8*)&ft[w * 32 + colr][kq * 32 + kg * 8];
    bf16x8 a1 = *(const bf16x8*)&ft[w * 32 + 16 + colr][kq * 32 + kg * 8];
    #pragma unroll
    for (int c = 0; c < 4; ++c) {
      acc[0][c] = __builtin_amdgcn_mfma_f32_16x16x32_bf16(a0, bfrag[c][kq], acc[0][c], 0, 0, 0);
      acc[1][c] = __builtin_amdgcn_mfma_f32_16x16x32_bf16(a1, bfrag[c][kq], acc[1][c], 0, 0, 0);
    }
  }

  #pragma unroll
  for (int m = 0; m < 2; ++m) {
    int nodeb = n0 + w * 32 + m * 16 + kg * 4;
    #pragma unroll
    for (int c = 0; c < 4; ++c) {
      #pragma unroll
      for (int r = 0; r < 4; ++r) {
        int node = nodeb + r;
        if (node < N) out[(size_t)node * 64 + c * 16 + colr] = acc[m][c][r];
      }
    }
  }
}

extern "C" void kernel_launch(void* const* d_in, const int* in_sizes, int n_in,
                              void* d_out, int out_size, void* d_ws, size_t ws_size,
                              hipStream_t stream) {
  const float* x      = (const float*)d_in[0];
  const int*   row    = (const int*)d_in[1];
  const int*   colptr = (const int*)d_in[2];
  const float* W      = (const float*)d_in[3];
  const float* b      = (const float*)d_in[4];
  float* out = (float*)d_out;

  int N = in_sizes[0] / 64;
  size_t nb_bf = (size_t)N * 64 * 2;   // bf16 x copy
  unsigned short* xb = (unsigned short*)d_ws;
  unsigned short* xa = (unsigned short*)((char*)d_ws + nb_bf);  // bf16 agg

  int total8 = N * 8;
  int nbc = (total8 + 255) / 256;
  int nba = (N + 3) / 4;
  int nbm = (N + 127) / 128;

  if (ws_size >= 2 * nb_bf) {
    cvt_bf16<<<nbc, 256, 0, stream>>>(x, xb, total8);
    agg_pair<true><<<nba, 256, 0, stream>>>(xb, row, colptr, out, xa, N);
    sage_mm<true, true><<<nbm, 256, 0, stream>>>(x, xb, xa, W, b, out, N);
  } else if (ws_size >= nb_bf) {
    cvt_bf16<<<nbc, 256, 0, stream>>>(x, xb, total8);
    agg_pair<false><<<nba, 256, 0, stream>>>(xb, row, colptr, out, xa, N);
    sage_mm<true, false><<<nbm, 256, 0, stream>>>(x, xb, xa, W, b, out, N);
  } else {
    agg_f32<<<nba, 256, 0, stream>>>(x, row, colptr, out, N);
    sage_mm<false, false><<<nbm, 256, 0, stream>>>(x, xb, xa, W, b, out, N);
  }
}